// Round 1
// baseline (167.159 us; speedup 1.0000x reference)
//
#include <hip/hip_runtime.h>
#include <math.h>

constexpr int BB = 64;
constexpr int DD = 8732;
constexpr int KK = 81;
constexpr int NBOX = BB * DD;

__device__ inline float smooth_l1(float d) {
    float z = fabsf(d);
    return z < 1.0f ? 0.5f * z * z : z - 0.5f;
}

// acc[0]=loc_sum, acc[1]=conf_sum, acc[2]=num_matched
__global__ void init_acc(double* acc) {
    if (threadIdx.x < 8) acc[threadIdx.x] = 0.0;
}

__global__ void __launch_bounds__(256) loc_kernel(const float4* __restrict__ lp,
                                                  const float4* __restrict__ lt,
                                                  const int* __restrict__ ct,
                                                  double* __restrict__ acc) {
    int i = blockIdx.x * 256 + threadIdx.x;
    float s = 0.0f;
    int c = 0;
    if (i < NBOX) {
        if (ct[i] > 0) {
            c = 1;
            float4 a = lp[i], b = lt[i];
            s = smooth_l1(a.x - b.x) + smooth_l1(a.y - b.y)
              + smooth_l1(a.z - b.z) + smooth_l1(a.w - b.w);
        }
    }
    double sd = (double)s;
    int cc = c;
    for (int o = 32; o; o >>= 1) {
        sd += __shfl_down(sd, o);
        cc += __shfl_down(cc, o);
    }
    __shared__ double s_s[4];
    __shared__ int s_c[4];
    int lane = threadIdx.x & 63, wid = threadIdx.x >> 6;
    if (lane == 0) { s_s[wid] = sd; s_c[wid] = cc; }
    __syncthreads();
    if (threadIdx.x == 0) {
        double t = s_s[0] + s_s[1] + s_s[2] + s_s[3];
        int tc = s_c[0] + s_c[1] + s_c[2] + s_c[3];
        atomicAdd(&acc[0], t);
        atomicAdd(&acc[2], (double)tc);
    }
}

// one wave (64 lanes) per box; K=81 logits -> lane holds x[lane], x[lane+64]
__global__ void __launch_bounds__(256) ce_kernel(const float* __restrict__ x,
                                                 const int* __restrict__ ct,
                                                 float* __restrict__ ce) {
    int wave = blockIdx.x * 4 + (threadIdx.x >> 6);
    int lane = threadIdx.x & 63;
    if (wave >= NBOX) return;
    const float* row = x + (size_t)wave * KK;
    float v0 = row[lane];
    bool has2 = (lane + 64) < KK;                 // lanes 0..16
    float v1 = has2 ? row[lane + 64] : -INFINITY;
    float m = fmaxf(v0, v1);
    for (int o = 32; o; o >>= 1) m = fmaxf(m, __shfl_xor(m, o));
    float e = __expf(v0 - m) + (has2 ? __expf(v1 - m) : 0.0f);
    for (int o = 32; o; o >>= 1) e += __shfl_xor(e, o);
    int y = ct[wave];                              // uniform across wave
    float xy = (y < 64) ? __shfl(v0, y) : __shfl(v1, y - 64);
    if (lane == 0) ce[wave] = logf(e) + m - xy;
}

// one block per batch row: hard-negative mining + selected CE sum
__global__ void __launch_bounds__(512) mine_kernel(const float* __restrict__ ce,
                                                   const int* __restrict__ ct,
                                                   double* __restrict__ acc) {
    __shared__ float cl[DD];       // 34928 B
    __shared__ int s_i[8];
    __shared__ double s_d[8];
    __shared__ int s_np;
    int b = blockIdx.x;
    const int* ctr = ct + b * DD;
    const float* cer = ce + b * DD;
    int tid = threadIdx.x;
    int lane = tid & 63, wid = tid >> 6;

    // num_pos for this row
    int cnt = 0;
    for (int j = tid; j < DD; j += 512) cnt += (ctr[j] > 0) ? 1 : 0;
    for (int o = 32; o; o >>= 1) cnt += __shfl_down(cnt, o);
    if (lane == 0) s_i[wid] = cnt;
    __syncthreads();
    if (tid == 0) {
        int np = 0;
        for (int k = 0; k < 8; k++) np += s_i[k];
        s_np = np;
    }
    __syncthreads();
    int num_pos = s_np;
    float numneg = fminf(3.0f * (float)num_pos, (float)(DD - 1));
    int M = DD - num_pos;          // count of non-pos boxes

    double sum = 0.0;
    if ((float)M <= numneg) {
        // top-T covers all non-pos boxes -> sel = all boxes in row
        // (any ce==0 non-pos corner case contributes 0 anyway)
        for (int j = tid; j < DD; j += 512) sum += (double)cer[j];
    } else {
        // exact general path: rank via stable-descending-count among non-pos
        for (int j = tid; j < DD; j += 512) cl[j] = (ctr[j] > 0) ? 0.0f : cer[j];
        __syncthreads();
        for (int i = tid; i < DD; i += 512) {
            if (ctr[i] > 0) { sum += (double)cer[i]; continue; }
            float ci = cl[i];
            int r = 0;
            for (int j = 0; j < DD; j++) {
                float cj = cl[j];
                r += (cj > ci || (cj == ci && j < i)) ? 1 : 0;
            }
            if ((float)r < numneg) sum += (double)cer[i];
        }
    }
    for (int o = 32; o; o >>= 1) sum += __shfl_down(sum, o);
    if (lane == 0) s_d[wid] = sum;
    __syncthreads();
    if (tid == 0) {
        double t = 0.0;
        for (int k = 0; k < 8; k++) t += s_d[k];
        atomicAdd(&acc[1], t);
    }
}

__global__ void fin_kernel(const double* __restrict__ acc, float* __restrict__ out) {
    if (threadIdx.x == 0) {
        double n = acc[2];
        double loc = acc[0] / n;
        double conf = acc[1] / n;
        out[0] = (float)(loc + conf);
        out[1] = (float)conf;
        out[2] = (float)loc;
    }
}

extern "C" void kernel_launch(void* const* d_in, const int* in_sizes, int n_in,
                              void* d_out, int out_size, void* d_ws, size_t ws_size,
                              hipStream_t stream) {
    const float4* lp = (const float4*)d_in[0];
    const float4* lt = (const float4*)d_in[1];
    const float* cp = (const float*)d_in[2];
    const int* ct = (const int*)d_in[3];
    float* out = (float*)d_out;
    double* acc = (double*)d_ws;
    float* ce = (float*)((char*)d_ws + 256);

    init_acc<<<1, 64, 0, stream>>>(acc);
    loc_kernel<<<(NBOX + 255) / 256, 256, 0, stream>>>(lp, lt, ct, acc);
    ce_kernel<<<(NBOX + 3) / 4, 256, 0, stream>>>(cp, ct, ce);
    mine_kernel<<<BB, 512, 0, stream>>>(ce, ct, acc);
    fin_kernel<<<1, 64, 0, stream>>>(acc, out);
}

// Round 2
// 83.929 us; speedup vs baseline: 1.9917x; 1.9917x over previous
//
#include <hip/hip_runtime.h>
#include <math.h>

constexpr int BB = 64;
constexpr int DD = 8732;
constexpr int KK = 81;
constexpr int NBOX = BB * DD;

__device__ inline float smooth_l1(float d) {
    float z = fabsf(d);
    return z < 1.0f ? 0.5f * z * z : z - 0.5f;
}

// acc[0]=loc_sum, acc[1]=conf_sum, acc[2]=num_matched
__global__ void init_acc(double* acc) {
    if (threadIdx.x < 8) acc[threadIdx.x] = 0.0;
}

// Thread-per-box: smooth-L1 (pos only) + per-box CE in one pass.
__global__ void __launch_bounds__(256) fused_kernel(const float4* __restrict__ lp,
                                                    const float4* __restrict__ lt,
                                                    const float* __restrict__ cp,
                                                    const int* __restrict__ ct,
                                                    float* __restrict__ ce,
                                                    double* __restrict__ acc) {
    int i = blockIdx.x * 256 + threadIdx.x;
    float locs = 0.0f;
    int c = 0;
    if (i < NBOX) {
        int y = ct[i];
        if (y > 0) {
            c = 1;
            float4 a = lp[i], b = lt[i];
            locs = smooth_l1(a.x - b.x) + smooth_l1(a.y - b.y)
                 + smooth_l1(a.z - b.z) + smooth_l1(a.w - b.w);
        }
        const float* row = cp + (size_t)i * KK;
        const float4* r4 = (const float4*)row;
        float v[81];
        #pragma unroll
        for (int j = 0; j < 20; ++j) {
            float4 t = r4[j];
            v[4 * j + 0] = t.x; v[4 * j + 1] = t.y;
            v[4 * j + 2] = t.z; v[4 * j + 3] = t.w;
        }
        v[80] = row[80];
        // 4-accumulator max tree (ILP)
        float m0 = v[0], m1 = v[1], m2 = v[2], m3 = v[3];
        #pragma unroll
        for (int j = 4; j < 80; j += 4) {
            m0 = fmaxf(m0, v[j + 0]); m1 = fmaxf(m1, v[j + 1]);
            m2 = fmaxf(m2, v[j + 2]); m3 = fmaxf(m3, v[j + 3]);
        }
        m0 = fmaxf(m0, v[80]);
        float m = fmaxf(fmaxf(m0, m1), fmaxf(m2, m3));
        // 4-accumulator exp-sum
        float s0 = 0.0f, s1 = 0.0f, s2 = 0.0f, s3 = 0.0f;
        #pragma unroll
        for (int j = 0; j < 80; j += 4) {
            s0 += __expf(v[j + 0] - m); s1 += __expf(v[j + 1] - m);
            s2 += __expf(v[j + 2] - m); s3 += __expf(v[j + 3] - m);
        }
        s0 += __expf(v[80] - m);
        float s = (s0 + s1) + (s2 + s3);
        float xy = row[y];     // L1 hit; avoids dynamic register indexing
        ce[i] = logf(s) + m - xy;
    }
    // block reduction: loc sum (double) + pos count
    double sd = (double)locs;
    int cc = c;
    for (int o = 32; o; o >>= 1) {
        sd += __shfl_down(sd, o);
        cc += __shfl_down(cc, o);
    }
    __shared__ double s_s[4];
    __shared__ int s_c[4];
    int lane = threadIdx.x & 63, wid = threadIdx.x >> 6;
    if (lane == 0) { s_s[wid] = sd; s_c[wid] = cc; }
    __syncthreads();
    if (threadIdx.x == 0) {
        double t = s_s[0] + s_s[1] + s_s[2] + s_s[3];
        int tc = s_c[0] + s_c[1] + s_c[2] + s_c[3];
        atomicAdd(&acc[0], t);
        atomicAdd(&acc[2], (double)tc);
    }
}

// one block per batch row: hard-negative mining + selected CE sum
__global__ void __launch_bounds__(512) mine_kernel(const float* __restrict__ ce,
                                                   const int* __restrict__ ct,
                                                   double* __restrict__ acc) {
    __shared__ float cl[DD];       // 34928 B
    __shared__ int s_i[8];
    __shared__ double s_d[8];
    __shared__ int s_np;
    int b = blockIdx.x;
    const int* ctr = ct + b * DD;
    const float* cer = ce + b * DD;
    int tid = threadIdx.x;
    int lane = tid & 63, wid = tid >> 6;

    int cnt = 0;
    for (int j = tid; j < DD; j += 512) cnt += (ctr[j] > 0) ? 1 : 0;
    for (int o = 32; o; o >>= 1) cnt += __shfl_down(cnt, o);
    if (lane == 0) s_i[wid] = cnt;
    __syncthreads();
    if (tid == 0) {
        int np = 0;
        for (int k = 0; k < 8; k++) np += s_i[k];
        s_np = np;
    }
    __syncthreads();
    int num_pos = s_np;
    float numneg = fminf(3.0f * (float)num_pos, (float)(DD - 1));
    int M = DD - num_pos;          // count of non-pos boxes

    double sum = 0.0;
    if ((float)M <= numneg) {
        // top-T covers all non-pos boxes -> sel = all boxes in row
        for (int j = tid; j < DD; j += 512) sum += (double)cer[j];
    } else {
        // exact general path: rank via stable-descending-count among non-pos
        for (int j = tid; j < DD; j += 512) cl[j] = (ctr[j] > 0) ? 0.0f : cer[j];
        __syncthreads();
        for (int i = tid; i < DD; i += 512) {
            if (ctr[i] > 0) { sum += (double)cer[i]; continue; }
            float ci = cl[i];
            int r = 0;
            for (int j = 0; j < DD; j++) {
                float cj = cl[j];
                r += (cj > ci || (cj == ci && j < i)) ? 1 : 0;
            }
            if ((float)r < numneg) sum += (double)cer[i];
        }
    }
    for (int o = 32; o; o >>= 1) sum += __shfl_down(sum, o);
    if (lane == 0) s_d[wid] = sum;
    __syncthreads();
    if (tid == 0) {
        double t = 0.0;
        for (int k = 0; k < 8; k++) t += s_d[k];
        atomicAdd(&acc[1], t);
    }
}

__global__ void fin_kernel(const double* __restrict__ acc, float* __restrict__ out) {
    if (threadIdx.x == 0) {
        double n = acc[2];
        double loc = acc[0] / n;
        double conf = acc[1] / n;
        out[0] = (float)(loc + conf);
        out[1] = (float)conf;
        out[2] = (float)loc;
    }
}

extern "C" void kernel_launch(void* const* d_in, const int* in_sizes, int n_in,
                              void* d_out, int out_size, void* d_ws, size_t ws_size,
                              hipStream_t stream) {
    const float4* lp = (const float4*)d_in[0];
    const float4* lt = (const float4*)d_in[1];
    const float* cp = (const float*)d_in[2];
    const int* ct = (const int*)d_in[3];
    float* out = (float*)d_out;
    double* acc = (double*)d_ws;
    float* ce = (float*)((char*)d_ws + 256);

    init_acc<<<1, 64, 0, stream>>>(acc);
    fused_kernel<<<(NBOX + 255) / 256, 256, 0, stream>>>(lp, lt, cp, ct, ce, acc);
    mine_kernel<<<BB, 512, 0, stream>>>(ce, ct, acc);
    fin_kernel<<<1, 64, 0, stream>>>(acc, out);
}

// Round 3
// 55.363 us; speedup vs baseline: 3.0194x; 1.5160x over previous
//
#include <hip/hip_runtime.h>
#include <math.h>

constexpr int BB = 64;
constexpr int DD = 8732;
constexpr int KK = 81;
constexpr int NBOX = BB * DD;            // 558848
constexpr int GPB = 64;                  // groups (boxes) per 256-thread block
constexpr int NBLK = NBOX / GPB;         // 8732
static_assert(NBOX % GPB == 0, "grid exact");

__device__ inline float smooth_l1(float d) {
    float z = fabsf(d);
    return z < 1.0f ? 0.5f * z * z : z - 0.5f;
}

// 4 lanes per box: coalesced conf loads (lane q owns float4 j=q+4t),
// group-reduce via 2 shuffles. No atomics: per-block partials to ws.
__global__ void __launch_bounds__(256) fused_kernel(
    const float4* __restrict__ lp, const float4* __restrict__ lt,
    const float* __restrict__ cp, const int* __restrict__ ct,
    float* __restrict__ ce, double* __restrict__ loc_part,
    int* __restrict__ cnt_part)
{
    int tid = threadIdx.x;
    int g = blockIdx.x * GPB + (tid >> 2);      // box id
    int q = tid & 3;                            // lane within 4-lane group
    const float* row = cp + (size_t)g * KK;
    const float4* r4 = (const float4*)row;
    float4 f[5];
    #pragma unroll
    for (int t = 0; t < 5; ++t) f[t] = r4[q + 4 * t];
    float v80 = row[80];

    float m = -INFINITY;
    #pragma unroll
    for (int t = 0; t < 5; ++t)
        m = fmaxf(m, fmaxf(fmaxf(f[t].x, f[t].y), fmaxf(f[t].z, f[t].w)));
    if (q == 0) m = fmaxf(m, v80);
    m = fmaxf(m, __shfl_xor(m, 1));
    m = fmaxf(m, __shfl_xor(m, 2));

    float s = 0.0f;
    #pragma unroll
    for (int t = 0; t < 5; ++t)
        s += __expf(f[t].x - m) + __expf(f[t].y - m)
           + __expf(f[t].z - m) + __expf(f[t].w - m);
    if (q == 0) s += __expf(v80 - m);
    s += __shfl_xor(s, 1);
    s += __shfl_xor(s, 2);

    int y = ct[g];                               // same for all 4 lanes
    float xv = row[y];                           // L1-hot reload; no dyn reg idx
    if (q == 0) ce[g] = logf(s) + m - xv;

    float locs = 0.0f;
    int c = 0;
    if (q == 1 && y > 0) {
        c = 1;
        float4 a = lp[g], b = lt[g];
        locs = smooth_l1(a.x - b.x) + smooth_l1(a.y - b.y)
             + smooth_l1(a.z - b.z) + smooth_l1(a.w - b.w);
    }
    for (int o = 32; o; o >>= 1) {
        locs += __shfl_down(locs, o);
        c    += __shfl_down(c, o);
    }
    __shared__ float s_l[4];
    __shared__ int   s_c[4];
    int lane = tid & 63, wid = tid >> 6;
    if (lane == 0) { s_l[wid] = locs; s_c[wid] = c; }
    __syncthreads();
    if (tid == 0) {
        loc_part[blockIdx.x] = (double)s_l[0] + (double)s_l[1]
                             + (double)s_l[2] + (double)s_l[3];
        cnt_part[blockIdx.x] = s_c[0] + s_c[1] + s_c[2] + s_c[3];
    }
}

// one block per batch row: hard-negative mining + selected CE sum (no atomics)
__global__ void __launch_bounds__(512) mine_kernel(const float* __restrict__ ce,
                                                   const int* __restrict__ ct,
                                                   double* __restrict__ row_conf) {
    __shared__ float cl[DD];
    __shared__ int s_i[8];
    __shared__ double s_d[8];
    __shared__ int s_np;
    int b = blockIdx.x;
    const int* ctr = ct + b * DD;
    const float* cer = ce + b * DD;
    int tid = threadIdx.x;
    int lane = tid & 63, wid = tid >> 6;

    int cnt = 0;
    for (int j = tid; j < DD; j += 512) cnt += (ctr[j] > 0) ? 1 : 0;
    for (int o = 32; o; o >>= 1) cnt += __shfl_down(cnt, o);
    if (lane == 0) s_i[wid] = cnt;
    __syncthreads();
    if (tid == 0) {
        int np = 0;
        for (int k = 0; k < 8; k++) np += s_i[k];
        s_np = np;
    }
    __syncthreads();
    int num_pos = s_np;
    float numneg = fminf(3.0f * (float)num_pos, (float)(DD - 1));
    int M = DD - num_pos;

    double sum = 0.0;
    if ((float)M <= numneg) {
        for (int j = tid; j < DD; j += 512) sum += (double)cer[j];
    } else {
        for (int j = tid; j < DD; j += 512) cl[j] = (ctr[j] > 0) ? 0.0f : cer[j];
        __syncthreads();
        for (int i = tid; i < DD; i += 512) {
            if (ctr[i] > 0) { sum += (double)cer[i]; continue; }
            float ci = cl[i];
            int r = 0;
            for (int j = 0; j < DD; j++) {
                float cj = cl[j];
                r += (cj > ci || (cj == ci && j < i)) ? 1 : 0;
            }
            if ((float)r < numneg) sum += (double)cer[i];
        }
    }
    for (int o = 32; o; o >>= 1) sum += __shfl_down(sum, o);
    if (lane == 0) s_d[wid] = sum;
    __syncthreads();
    if (tid == 0) {
        double t = 0.0;
        for (int k = 0; k < 8; k++) t += s_d[k];
        row_conf[b] = t;
    }
}

__global__ void __launch_bounds__(256) fin_kernel(const double* __restrict__ loc_part,
                                                  const int* __restrict__ cnt_part,
                                                  const double* __restrict__ row_conf,
                                                  float* __restrict__ out) {
    int tid = threadIdx.x;
    double l = 0.0, cf = 0.0, n = 0.0;
    for (int j = tid; j < NBLK; j += 256) {
        l += loc_part[j];
        n += (double)cnt_part[j];
    }
    if (tid < BB) cf = row_conf[tid];
    for (int o = 32; o; o >>= 1) {
        l  += __shfl_down(l, o);
        cf += __shfl_down(cf, o);
        n  += __shfl_down(n, o);
    }
    __shared__ double sl[4], sc[4], sn[4];
    int lane = tid & 63, wid = tid >> 6;
    if (lane == 0) { sl[wid] = l; sc[wid] = cf; sn[wid] = n; }
    __syncthreads();
    if (tid == 0) {
        double L = sl[0] + sl[1] + sl[2] + sl[3];
        double C = sc[0] + sc[1] + sc[2] + sc[3];
        double N = sn[0] + sn[1] + sn[2] + sn[3];
        out[0] = (float)(L / N + C / N);
        out[1] = (float)(C / N);
        out[2] = (float)(L / N);
    }
}

extern "C" void kernel_launch(void* const* d_in, const int* in_sizes, int n_in,
                              void* d_out, int out_size, void* d_ws, size_t ws_size,
                              hipStream_t stream) {
    const float4* lp = (const float4*)d_in[0];
    const float4* lt = (const float4*)d_in[1];
    const float* cp = (const float*)d_in[2];
    const int* ct = (const int*)d_in[3];
    float* out = (float*)d_out;

    char* w = (char*)d_ws;
    double* loc_part = (double*)w;                        // 8732 doubles
    int*    cnt_part = (int*)(w + 8736 * 8);              // 8732 ints
    double* row_conf = (double*)(w + 8736 * 8 + 8736 * 4);// 64 doubles
    float*  ce       = (float*)(w + 8736 * 8 + 8736 * 4 + 512);

    fused_kernel<<<NBLK, 256, 0, stream>>>(lp, lt, cp, ct, ce, loc_part, cnt_part);
    mine_kernel<<<BB, 512, 0, stream>>>(ce, ct, row_conf);
    fin_kernel<<<1, 256, 0, stream>>>(loc_part, cnt_part, row_conf, out);
}

// Round 4
// 48.377 us; speedup vs baseline: 3.4554x; 1.1444x over previous
//
#include <hip/hip_runtime.h>
#include <math.h>

constexpr int BB = 64;
constexpr int DD = 8732;
constexpr int KK = 81;
constexpr int NBOX = BB * DD;            // 558848
constexpr int SL = 137;                  // slices per row (137*64 >= 8732)
constexpr int NPART = BB * SL;           // 8768

__device__ inline float smooth_l1(float d) {
    float z = fabsf(d);
    return z < 1.0f ? 0.5f * z * z : z - 0.5f;
}

// Grid (slice, row). Block = 256 threads = 64 boxes x 4 lanes.
// Per-block partials: pos_count, ce_sum, loc_sum -> no global re-read for mining.
__global__ void __launch_bounds__(256) fused_kernel(
    const float4* __restrict__ lp, const float4* __restrict__ lt,
    const float* __restrict__ cp, const int* __restrict__ ct,
    float* __restrict__ ce, int* __restrict__ cnt_part,
    float* __restrict__ ce_part, float* __restrict__ loc_part)
{
    int tid = threadIdx.x;
    int slice = blockIdx.x, row = blockIdx.y;
    int bir = slice * 64 + (tid >> 2);          // box index within row
    int q = tid & 3;
    bool active = bir < DD;
    float ce_c = 0.0f, locs = 0.0f;
    int c = 0;
    if (active) {
        size_t g = (size_t)row * DD + bir;
        const float* rowp = cp + g * KK;
        const float4* r4 = (const float4*)rowp;
        float4 f[5];
        #pragma unroll
        for (int t = 0; t < 5; ++t) f[t] = r4[q + 4 * t];
        float v80 = rowp[80];

        float m = -INFINITY;
        #pragma unroll
        for (int t = 0; t < 5; ++t)
            m = fmaxf(m, fmaxf(fmaxf(f[t].x, f[t].y), fmaxf(f[t].z, f[t].w)));
        if (q == 0) m = fmaxf(m, v80);
        m = fmaxf(m, __shfl_xor(m, 1));
        m = fmaxf(m, __shfl_xor(m, 2));

        float s = 0.0f;
        #pragma unroll
        for (int t = 0; t < 5; ++t)
            s += __expf(f[t].x - m) + __expf(f[t].y - m)
               + __expf(f[t].z - m) + __expf(f[t].w - m);
        if (q == 0) s += __expf(v80 - m);
        s += __shfl_xor(s, 1);
        s += __shfl_xor(s, 2);

        int y = ct[g];                           // uniform across the 4 lanes
        float xv = rowp[y];                      // L1-hot; avoids dyn reg idx
        float cev = __logf(s) + m - xv;
        if (q == 0) { ce[g] = cev; ce_c = cev; }
        if (q == 1 && y > 0) {
            c = 1;
            float4 a = lp[g], b = lt[g];
            locs = smooth_l1(a.x - b.x) + smooth_l1(a.y - b.y)
                 + smooth_l1(a.z - b.z) + smooth_l1(a.w - b.w);
        }
    }
    for (int o = 32; o; o >>= 1) {
        locs += __shfl_down(locs, o);
        ce_c += __shfl_down(ce_c, o);
        c    += __shfl_down(c, o);
    }
    __shared__ float s_l[4], s_e[4];
    __shared__ int   s_c[4];
    int lane = tid & 63, wid = tid >> 6;
    if (lane == 0) { s_l[wid] = locs; s_e[wid] = ce_c; s_c[wid] = c; }
    __syncthreads();
    if (tid == 0) {
        int idx = row * SL + slice;
        loc_part[idx] = s_l[0] + s_l[1] + s_l[2] + s_l[3];
        ce_part[idx]  = s_e[0] + s_e[1] + s_e[2] + s_e[3];
        cnt_part[idx] = s_c[0] + s_c[1] + s_c[2] + s_c[3];
    }
}

// one block per row: fast path = pure partial reduction (no ce re-read);
// exact O(D*M) fallback kept for generality.
__global__ void __launch_bounds__(256) mine_kernel(
    const int* __restrict__ cnt_part, const float* __restrict__ ce_part,
    const float* __restrict__ ce, const int* __restrict__ ct,
    double* __restrict__ row_conf)
{
    __shared__ double s_d[4];
    __shared__ int s_i[4];
    __shared__ int s_np;
    __shared__ double s_tot;
    __shared__ float cl[DD];
    int r = blockIdx.x, tid = threadIdx.x;
    int lane = tid & 63, wid = tid >> 6;

    int cnt = 0; double tot = 0.0;
    if (tid < SL) { cnt = cnt_part[r * SL + tid]; tot = (double)ce_part[r * SL + tid]; }
    for (int o = 32; o; o >>= 1) { cnt += __shfl_down(cnt, o); tot += __shfl_down(tot, o); }
    if (lane == 0) { s_i[wid] = cnt; s_d[wid] = tot; }
    __syncthreads();
    if (tid == 0) {
        s_np  = s_i[0] + s_i[1] + s_i[2] + s_i[3];
        s_tot = s_d[0] + s_d[1] + s_d[2] + s_d[3];
    }
    __syncthreads();
    int num_pos = s_np;
    float numneg = fminf(3.0f * (float)num_pos, (float)(DD - 1));
    int M = DD - num_pos;
    if ((float)M <= numneg) {              // all boxes selected
        if (tid == 0) row_conf[r] = s_tot;
        return;
    }
    // exact general path (not taken for this data)
    const int* ctr = ct + r * DD;
    const float* cer = ce + r * DD;
    double sum = 0.0;
    for (int j = tid; j < DD; j += 256) cl[j] = (ctr[j] > 0) ? 0.0f : cer[j];
    __syncthreads();
    for (int i = tid; i < DD; i += 256) {
        if (ctr[i] > 0) { sum += (double)cer[i]; continue; }
        float ci = cl[i];
        int rk = 0;
        for (int j = 0; j < DD; j++) {
            float cj = cl[j];
            rk += (cj > ci || (cj == ci && j < i)) ? 1 : 0;
        }
        if ((float)rk < numneg) sum += (double)cer[i];
    }
    for (int o = 32; o; o >>= 1) sum += __shfl_down(sum, o);
    if (lane == 0) s_d[wid] = sum;
    __syncthreads();
    if (tid == 0) row_conf[r] = s_d[0] + s_d[1] + s_d[2] + s_d[3];
}

__global__ void __launch_bounds__(256) fin_kernel(
    const float* __restrict__ loc_part, const int* __restrict__ cnt_part,
    const double* __restrict__ row_conf, float* __restrict__ out)
{
    int tid = threadIdx.x;
    double l = 0.0, n = 0.0, cf = 0.0;
    for (int j = tid; j < NPART; j += 256) {
        l += (double)loc_part[j];
        n += (double)cnt_part[j];
    }
    if (tid < BB) cf = row_conf[tid];
    for (int o = 32; o; o >>= 1) {
        l  += __shfl_down(l, o);
        cf += __shfl_down(cf, o);
        n  += __shfl_down(n, o);
    }
    __shared__ double sl[4], sc[4], sn[4];
    int lane = tid & 63, wid = tid >> 6;
    if (lane == 0) { sl[wid] = l; sc[wid] = cf; sn[wid] = n; }
    __syncthreads();
    if (tid == 0) {
        double L = sl[0] + sl[1] + sl[2] + sl[3];
        double C = sc[0] + sc[1] + sc[2] + sc[3];
        double N = sn[0] + sn[1] + sn[2] + sn[3];
        out[0] = (float)(L / N + C / N);
        out[1] = (float)(C / N);
        out[2] = (float)(L / N);
    }
}

extern "C" void kernel_launch(void* const* d_in, const int* in_sizes, int n_in,
                              void* d_out, int out_size, void* d_ws, size_t ws_size,
                              hipStream_t stream) {
    const float4* lp = (const float4*)d_in[0];
    const float4* lt = (const float4*)d_in[1];
    const float* cp = (const float*)d_in[2];
    const int* ct = (const int*)d_in[3];
    float* out = (float*)d_out;

    char* w = (char*)d_ws;
    int*    cnt_part = (int*)w;                       // 8768 ints   (35072 B)
    float*  loc_part = (float*)(w + 35072);           // 8768 floats
    float*  ce_part  = (float*)(w + 70144);           // 8768 floats
    double* row_conf = (double*)(w + 105216);         // 64 doubles
    float*  ce       = (float*)(w + 105728);          // NBOX floats

    dim3 grid(SL, BB);
    fused_kernel<<<grid, 256, 0, stream>>>(lp, lt, cp, ct, ce,
                                           cnt_part, ce_part, loc_part);
    mine_kernel<<<BB, 256, 0, stream>>>(cnt_part, ce_part, ce, ct, row_conf);
    fin_kernel<<<1, 256, 0, stream>>>(loc_part, cnt_part, row_conf, out);
}